// Round 1
// 2301.183 us; speedup vs baseline: 1.1927x; 1.1927x over previous
//
#include <hip/hip_runtime.h>
#include <stdint.h>

// LSTM B=256,T=512,F=32,U=350; gates i,f,g(relu),o; h=o*relu(c); out=h.dw+db
//
// R8: keep the h exchange resident in the XCD-local L2.
//  R7 counters: WRITE_SIZE 186MB == h-store bytes, FETCH_SIZE 192MB == h reads
//  + x, exactly ONE 22.5KB slab fetch per group-step -> AGENT-scope stores
//  write through/past L2, first consumer pays an HBM round trip every step
//  (~900cy) plus spin granularity = 5.4us/step, MfmaUtil 2%.
//  Change:
//   - FAST buffer (hbuf): producers store h with WORKGROUP-scope (plain,
//     writeback) stores. All 11 blocks of a group sit on one XCD
//     (grp = blockIdx&15, XCD = blockIdx%8, 16 % 8 == 0), so the slab stays
//     dirty in that XCD's L2. Consumers keep AGENT-scope loads (L1-bypass,
//     L2-hit -- R7 counters prove agent loads are served by L2).
//   - MIRROR buffer (hmir): producers ALSO fire AGENT-scope stores
//     (write-through, fire-and-forget, off the critical path). Consumers
//     switch to the mirror after 48 failed fast attempts: correctness does
//     NOT depend on the blockIdx->XCD mapping; worst case ~= R7 speed.
//  Tag-in-word protocol unchanged (word-atomic data+tag; depth-2 ping-pong
//  proof carries over: a reader's progress signal is its own next write,
//  regardless of which buffer served its read). Tag check tightened:
//  accumulate OR of (word^tag), mask 0xFFFF once at the end.

#define T_   512
#define F_   32
#define U_   350
#define G4   1400
#define NGRP 16
#define NB   16
#define NCB  11
#define KC   12
#define NT   88
#define HROW 352         // f32 words per h row (350 + bias-1.0 col + zero col)

typedef __attribute__((ext_vector_type(8))) short  short8;
typedef __attribute__((ext_vector_type(4))) short  short4_;
typedef __attribute__((ext_vector_type(4))) float  float4_;
typedef unsigned long long u64t;

__device__ __forceinline__ short f2bf(float f) {
  union { float f; uint32_t u; } v; v.f = f;
  return (short)((v.u + 0x7FFFu + ((v.u >> 16) & 1u)) >> 16);
}

// ---- workspace layout (bytes) ----
#define SZ_W     (NT*KC*64*8*2u)                        // 1,081,344
#define OFF_XBF  (SZ_W)
#define SZ_XBF   (256u*T_*F_*2u)                        // 8,388,608
#define OFF_HBUF (OFF_XBF + SZ_XBF)
#define SZ_HBUF  (NGRP*2u*NB*HROW*4u)                   // 720,896 (f32 words)
#define OFF_HMIR (OFF_HBUF + SZ_HBUF)
#define OFF_WP   (OFF_HMIR + SZ_HBUF)
#define SZ_WP    (NGRP*NCB*NB*T_*4u)                    // 5,767,168

// ---- prep: W_swz[kc][tile][lane][8] bf16 in MFMA B-fragment order ----
__global__ void prep_w(const float* __restrict__ kern,
                       const float* __restrict__ rk,
                       const float* __restrict__ bias,
                       short* __restrict__ wswz) {
  const int tile = blockIdx.x, lane = threadIdx.x;
  const int g = tile / 22, jt = tile % 22;
  const int colg = jt * 16 + (lane & 15);
  const int src = g * U_ + colg;
  const bool valid = (colg < U_);
  const int kbase = (lane >> 4) * 8;
  for (int kc = 0; kc < KC; ++kc) {
    short8 pack;
    #pragma unroll
    for (int jj = 0; jj < 8; ++jj) {
      int k = kc * 32 + kbase + jj;
      float v = 0.f;
      if (valid) {
        if (k < F_)            v = kern[k * G4 + src];
        else if (k < F_ + U_)  v = rk[(k - F_) * G4 + src];
        else if (k == F_ + U_) v = bias[src];
      }
      pack[jj] = f2bf(v);
    }
    *(short8*)(wswz + (((size_t)kc * NT + tile) * 64 + lane) * 8) = pack;
  }
}

// ---- prep: x f32 -> bf16 ([b][t][f], contiguous 16B A-frag loads) ----
__global__ void prep_x(const float* __restrict__ x, short* __restrict__ xbf) {
  int i = (blockIdx.x * 256 + threadIdx.x) * 4;
  float4_ v = *(const float4_*)(x + i);
  short4_ o;
  #pragma unroll
  for (int jj = 0; jj < 4; ++jj) o[jj] = f2bf(v[jj]);
  *(short4_*)(xbf + i) = o;
}

// ---- init: slot1 = h_{-1}=0 with tag 0 (bias col 350 = bf16 1.0), both bufs.
// Slot 0 needs no init: step-1 readers expect tag 1 and retry over poison.
// Kernel-boundary release/acquire flushes these to the coherent point before
// lstm_kernel starts, so first fast-path reads miss L2 and fetch fresh data.
__global__ void init_all(uint32_t* __restrict__ hbuf32,
                         uint32_t* __restrict__ hmir32) {
  int i = blockIdx.x * 256 + threadIdx.x;        // 90112 threads
  int c = i % HROW;
  int grp = i / (NB * HROW), rem = i % (NB * HROW);
  uint32_t v = (c == 350) ? 0x3F800000u : 0u;
  size_t idx = (size_t)(grp * 2 + 1) * NB * HROW + rem;
  hbuf32[idx] = v;
  hmir32[idx] = v;
}

// ---- main: persistent, 2 decoupled waves per block, weights in regs ----
__global__ __launch_bounds__(128)
__attribute__((amdgpu_waves_per_eu(1, 1)))
void lstm_kernel(const short* __restrict__ xbf, const short* __restrict__ wswz,
                 uint32_t* __restrict__ hbuf32, uint32_t* __restrict__ hmir32,
                 const float* __restrict__ dense_w, float* __restrict__ wpart) {
  __shared__ float lds_part[2][T_][16];   // 64 KB dense-head partials

  const int tid  = threadIdx.x;
  const int lane = tid & 63;
  const int wv   = tid >> 6;            // 0..1
  const int l15  = lane & 15;
  const int quad = lane >> 4;
  const int grp  = blockIdx.x & 15;     // same-XCD heuristic (fast path only)
  const int j    = blockIdx.x >> 4;     // 0..10
  const int tileg = 2 * j + wv;         // this wave's col tile 0..21

  // weights -> registers ONCE: 192 regs/lane
  short8 wreg[4][KC];
  #pragma unroll
  for (int g = 0; g < 4; ++g)
    #pragma unroll
    for (int kc = 0; kc < KC; ++kc)
      wreg[g][kc] = *(const short8*)(wswz +
          (((size_t)kc * NT + (g * 22 + tileg)) * 64 + lane) * 8);

  const int col = tileg * 16 + l15;               // gate-relative col 0..351
  const float dwv = (col < U_) ? dense_w[col] : 0.f;
  float cst[4] = {0.f, 0.f, 0.f, 0.f};

  const short* xrow = xbf + ((size_t)(grp * NB + l15) * T_) * F_ + quad * 8;
  uint32_t* hb = hbuf32 + (size_t)grp * 2 * NB * HROW;
  uint32_t* hm = hmir32 + (size_t)grp * 2 * NB * HROW;

  #pragma unroll 1
  for (int t = 0; t < T_; ++t) {
    short8 axf = *(const short8*)(xrow + t * F_);

    // kc=0 (x-only) MFMA — h-independent, overlaps first h-load flight
    float4_ acc[4];
    #pragma unroll
    for (int g = 0; g < 4; ++g) {
      float4_ z = (float4_){0.f, 0.f, 0.f, 0.f};
      acc[g] = __builtin_amdgcn_mfma_f32_16x16x32_bf16(axf, wreg[g][0], z, 0, 0, 0);
    }

    // tag-verified h A-frag load from slot (t-1)&1 == (t+1)&1
    // lane covers row l15, h cols (kc-1)*32 + quad*8 .. +8  (as f32 words)
    const uint32_t tag = (uint32_t)t & 0xFFFFu;
    const size_t slotr = ((size_t)((t + 1) & 1)) * NB * HROW
                       + (size_t)l15 * HROW + quad * 8;
    const uint32_t* hq  = hb + slotr;   // fast: XCD-local L2
    const uint32_t* hqm = hm + slotr;   // mirror: coherent fallback
    u64t q[44];
    bool okall;
    int tries = 0;
    do {
      #pragma unroll
      for (int i = 0; i < 11; ++i) {
        const u64t* p = (const u64t*)(hq + i * 32);
        q[4 * i + 0] = __hip_atomic_load(p + 0, __ATOMIC_RELAXED, __HIP_MEMORY_SCOPE_AGENT);
        q[4 * i + 1] = __hip_atomic_load(p + 1, __ATOMIC_RELAXED, __HIP_MEMORY_SCOPE_AGENT);
        q[4 * i + 2] = __hip_atomic_load(p + 2, __ATOMIC_RELAXED, __HIP_MEMORY_SCOPE_AGENT);
        q[4 * i + 3] = __hip_atomic_load(p + 3, __ATOMIC_RELAXED, __HIP_MEMORY_SCOPE_AGENT);
      }
      uint32_t bad = 0;
      #pragma unroll
      for (int i = 0; i < 44; ++i) {
        bad |= ((uint32_t)q[i] ^ tag);
        bad |= ((uint32_t)(q[i] >> 32) ^ tag);
      }
      okall = (bool)__all((int)((bad & 0xFFFFu) == 0));
      if (!okall && ++tries >= 48) hq = hqm;  // uniform switch, no deadlock
    } while (!okall);

    // repack hi16 pairs -> bf16 A-frags; MFMA over kc=1..11
    #pragma unroll
    for (int i = 0; i < 11; ++i) {
      union { uint32_t w[4]; short8 s; } u;
      #pragma unroll
      for (int k = 0; k < 4; ++k) {
        uint32_t lo = (uint32_t)q[4 * i + k];
        uint32_t hi = (uint32_t)(q[4 * i + k] >> 32);
        u.w[k] = (lo >> 16) | (hi & 0xFFFF0000u);
      }
      #pragma unroll
      for (int g = 0; g < 4; ++g)
        acc[g] = __builtin_amdgcn_mfma_f32_16x16x32_bf16(u.s, wreg[g][i + 1], acc[g], 0, 0, 0);
    }

    // update: lane covers rows quad*4+r at its col; gates in registers
    uint32_t* hwr  = hb + ((size_t)(t & 1)) * NB * HROW;
    uint32_t* hwrm = hm + ((size_t)(t & 1)) * NB * HROW;
    const uint32_t otag = (uint32_t)(t + 1) & 0xFFFFu;
    float hn[4];
    uint32_t wout[4];
    #pragma unroll
    for (int r = 0; r < 4; ++r) {
      float ig = __builtin_amdgcn_rcpf(1.f + __expf(-acc[0][r]));
      float fg = __builtin_amdgcn_rcpf(1.f + __expf(-acc[1][r]));
      float gg = fmaxf(acc[2][r], 0.f);
      float og = __builtin_amdgcn_rcpf(1.f + __expf(-acc[3][r]));
      float cn = fg * cst[r] + ig * gg;
      cst[r] = cn;
      hn[r] = og * fmaxf(cn, 0.f);
      short hs = f2bf(hn[r]);
      if (col == 350) hs = (short)0x3F80;        // bias-row input stays 1.0
      else if (col == 351) hs = 0;
      wout[r] = ((uint32_t)(unsigned short)hs << 16) | otag;
      // FAST: plain writeback store — stays dirty in the group's XCD L2
      __hip_atomic_store(hwr + (quad * 4 + r) * HROW + col, wout[r],
                         __ATOMIC_RELAXED, __HIP_MEMORY_SCOPE_WORKGROUP);
    }
    // MIRROR: agent write-through (fire-and-forget, off critical path)
    #pragma unroll
    for (int r = 0; r < 4; ++r)
      __hip_atomic_store(hwrm + (quad * 4 + r) * HROW + col, wout[r],
                         __ATOMIC_RELAXED, __HIP_MEMORY_SCOPE_AGENT);

    // dense head (off the critical path), into LDS
    #pragma unroll
    for (int r = 0; r < 4; ++r) {
      float s = hn[r] * dwv;
      s += __shfl_xor(s, 1); s += __shfl_xor(s, 2);
      s += __shfl_xor(s, 4); s += __shfl_xor(s, 8);
      if (l15 == 0) lds_part[wv][t][quad * 4 + r] = s;
    }
  }

  // bulk-store dense partials (once)
  __syncthreads();
  float* wp = wpart + ((size_t)(grp * NCB + j) * NB) * T_;
  for (int i = tid; i < NB * T_; i += 128) {
    int t = i & (T_ - 1), row = i >> 9;
    wp[(size_t)row * T_ + t] = lds_part[0][t][row] + lds_part[1][t][row];
  }
}

// ---- final: out[b,t] = db + sum_j wpart[grp][j][row][t] ----
__global__ void reduce_out(const float* __restrict__ wpart,
                           const float* __restrict__ dense_b,
                           float* __restrict__ out) {
  int i = blockIdx.x * 256 + threadIdx.x;   // i = b*T + t
  int b = i >> 9, t = i & 511;
  int grp = b >> 4, row = b & 15;
  float s = dense_b[0];
  #pragma unroll
  for (int j = 0; j < NCB; ++j)
    s += wpart[(((size_t)grp * NCB + j) * NB + row) * T_ + t];
  out[i] = s;
}

extern "C" void kernel_launch(void* const* d_in, const int* in_sizes, int n_in,
                              void* d_out, int out_size, void* d_ws, size_t ws_size,
                              hipStream_t stream) {
  const float* x    = (const float*)d_in[0];
  const float* kern = (const float*)d_in[1];
  const float* rk   = (const float*)d_in[2];
  const float* bias = (const float*)d_in[3];
  const float* dw   = (const float*)d_in[4];
  const float* db   = (const float*)d_in[5];
  float* out = (float*)d_out;

  char* ws = (char*)d_ws;
  short*    wswz   = (short*)(ws);
  short*    xbf    = (short*)(ws + OFF_XBF);
  uint32_t* hbuf32 = (uint32_t*)(ws + OFF_HBUF);
  uint32_t* hmir32 = (uint32_t*)(ws + OFF_HMIR);
  float*    wpart  = (float*)(ws + OFF_WP);

  prep_w<<<NT, 64, 0, stream>>>(kern, rk, bias, wswz);
  prep_x<<<(256 * T_ * F_) / (256 * 4), 256, 0, stream>>>(x, xbf);
  init_all<<<(NGRP * NB * HROW) / 256, 256, 0, stream>>>(hbuf32, hmir32);
  lstm_kernel<<<NGRP * NCB, 128, 0, stream>>>(xbf, wswz, hbuf32, hmir32, dw, wpart);
  reduce_out<<<(256 * T_) / 256, 256, 0, stream>>>(wpart, db, out);
}

// Round 3
// 1337.169 us; speedup vs baseline: 2.0526x; 1.7209x over previous
//
#include <hip/hip_runtime.h>
#include <stdint.h>

// LSTM B=256,T=512,F=32,U=350; gates i,f,g(relu),o; h=o*relu(c); out=h.dw+db
//
// R10: coalesced h-slot layout, zero inline asm (R9 postmortem: container
//  died; inline-asm spin loads were the least-proven construct — reverted).
//  Control flow / atomic-op style is byte-identical to the PASSING R8;
//  only the address maps changed:
//   - slot layout: word(row,col) at (i*2+k2)*256 + (quadc*16+row)*4 + k1*2+b
//     (i=col/32, quadc=(col%32)/8, k2=(col%8)/4, k1=(col%4)/2, b=col&1).
//     Consumer lane L (row=L&15, quad=L>>4) reads its A-frag as 16
//     CONTIGUOUS bytes at blk*1024 + L*16 (blk=i*2+k2): per kc-block the
//     wave issues 4 u64 agent loads covering 1KB contiguous — every 64B
//     line requested ONCE and fully consumed. R8's pattern touched each
//     line 2x with half wasted (~704 line-req/wave/attempt vs 352 now);
//     44 waves/XCD x 704 ~= 31k req/attempt-round ~= the measured 10.8k
//     cy/step. Halving requests + full line use should ~halve step time.
//   - producer: 4 stores at +16B stride into 1-2 lines (was 16 scattered).
//   - MIRROR buffer: same layout as fast buffer; fallback after 48 failed
//     tries = switch base pointer (identical to R8). Correctness never
//     depends on blockIdx->XCD mapping.
//  Tag-in-word protocol, depth-2 ping-pong proof, gate math unchanged.

#define T_   512
#define F_   32
#define U_   350
#define G4   1400
#define NGRP 16
#define NB   16
#define NCB  11
#define KC   12
#define NT   88
#define SLOTW 5632      // words per h slot (16 rows x 352 cols)

typedef __attribute__((ext_vector_type(8))) short  short8;
typedef __attribute__((ext_vector_type(4))) short  short4_;
typedef __attribute__((ext_vector_type(4))) float  float4_;
typedef unsigned long long u64t;

__device__ __forceinline__ short f2bf(float f) {
  union { float f; uint32_t u; } v; v.f = f;
  return (short)((v.u + 0x7FFFu + ((v.u >> 16) & 1u)) >> 16);
}

// ---- workspace layout (bytes) ----
#define SZ_W     (NT*KC*64*8*2u)                        // 1,081,344
#define OFF_XBF  (SZ_W)
#define SZ_XBF   (256u*T_*F_*2u)                        // 8,388,608
#define OFF_HBUF (OFF_XBF + SZ_XBF)
#define SZ_HBUF  (NGRP*2u*SLOTW*4u)                     // 720,896
#define OFF_HMIR (OFF_HBUF + SZ_HBUF)
#define OFF_WP   (OFF_HMIR + SZ_HBUF)
#define SZ_WP    (NGRP*NCB*NB*T_*4u)                    // 5,767,168

// ---- prep: W_swz[kc][tile][lane][8] bf16 in MFMA B-fragment order ----
__global__ void prep_w(const float* __restrict__ kern,
                       const float* __restrict__ rk,
                       const float* __restrict__ bias,
                       short* __restrict__ wswz) {
  const int tile = blockIdx.x, lane = threadIdx.x;
  const int g = tile / 22, jt = tile % 22;
  const int colg = jt * 16 + (lane & 15);
  const int src = g * U_ + colg;
  const bool valid = (colg < U_);
  const int kbase = (lane >> 4) * 8;
  for (int kc = 0; kc < KC; ++kc) {
    short8 pack;
    #pragma unroll
    for (int jj = 0; jj < 8; ++jj) {
      int k = kc * 32 + kbase + jj;
      float v = 0.f;
      if (valid) {
        if (k < F_)            v = kern[k * G4 + src];
        else if (k < F_ + U_)  v = rk[(k - F_) * G4 + src];
        else if (k == F_ + U_) v = bias[src];
      }
      pack[jj] = f2bf(v);
    }
    *(short8*)(wswz + (((size_t)kc * NT + tile) * 64 + lane) * 8) = pack;
  }
}

// ---- prep: x f32 -> bf16 ([b][t][f], contiguous 16B A-frag loads) ----
__global__ void prep_x(const float* __restrict__ x, short* __restrict__ xbf) {
  int i = (blockIdx.x * 256 + threadIdx.x) * 4;
  float4_ v = *(const float4_*)(x + i);
  short4_ o;
  #pragma unroll
  for (int jj = 0; jj < 4; ++jj) o[jj] = f2bf(v[jj]);
  *(short4_*)(xbf + i) = o;
}

// ---- init: slot1 = h_{-1}=0 with tag 0 (bias col 350 = bf16 1.0) ----
// Both buffers share the fast layout now. Slot 0 needs no init: step-1
// readers expect tag 1 and retry over poison.
__global__ void init_all(uint32_t* __restrict__ hbuf32,
                         uint32_t* __restrict__ hmir32) {
  int i = blockIdx.x * 256 + threadIdx.x;            // 0 .. NGRP*SLOTW-1
  int grp = i / SLOTW, rem = i % SLOTW;
  // rem = (fi*2+fk2)*256 + (fquadc*16+row)*4 + fk1*2 + fb
  int blk = rem >> 8, off = rem & 255;
  int fi = blk >> 1, fk2 = blk & 1, fquadc = off >> 6;
  int fk1 = (off >> 1) & 1, fb = off & 1;
  int fcol = fi * 32 + fquadc * 8 + fk2 * 4 + fk1 * 2 + fb;
  uint32_t v = (fcol == 350) ? 0x3F800000u : 0u;
  size_t idx = (size_t)(grp * 2 + 1) * SLOTW + rem;
  hbuf32[idx] = v;
  hmir32[idx] = v;
}

// ---- main: persistent, 2 decoupled waves per block, weights in regs ----
__global__ __launch_bounds__(128)
__attribute__((amdgpu_waves_per_eu(1, 1)))
void lstm_kernel(const short* __restrict__ xbf, const short* __restrict__ wswz,
                 uint32_t* __restrict__ hbuf32, uint32_t* __restrict__ hmir32,
                 const float* __restrict__ dense_w, float* __restrict__ wpart) {
  __shared__ float lds_part[2][T_][16];   // 64 KB dense-head partials

  const int tid  = threadIdx.x;
  const int lane = tid & 63;
  const int wv   = tid >> 6;            // 0..1
  const int l15  = lane & 15;
  const int quad = lane >> 4;
  const int grp  = blockIdx.x & 15;     // same-XCD heuristic (fast path only)
  const int j    = blockIdx.x >> 4;     // 0..10
  const int tileg = 2 * j + wv;         // this wave's col tile 0..21

  // weights -> registers ONCE
  short8 wreg[4][KC];
  #pragma unroll
  for (int g = 0; g < 4; ++g)
    #pragma unroll
    for (int kc = 0; kc < KC; ++kc)
      wreg[g][kc] = *(const short8*)(wswz +
          (((size_t)kc * NT + (g * 22 + tileg)) * 64 + lane) * 8);

  const int col = tileg * 16 + l15;               // gate-relative col 0..351
  const float dwv = (col < U_) ? dense_w[col] : 0.f;
  float cst[4] = {0.f, 0.f, 0.f, 0.f};

  // producer store offset (words within slot), +r*4 per row
  const int colrem = col & 31;
  const int fastoff = (((col >> 5) * 2 + ((colrem >> 2) & 1)) * 256)
                    + (((colrem >> 3) * 16 + quad * 4) * 4)
                    + (((colrem >> 1) & 1) * 2) + (col & 1);

  const short* xrow = xbf + ((size_t)(grp * NB + l15) * T_) * F_ + quad * 8;
  uint32_t* hb = hbuf32 + (size_t)grp * 2 * SLOTW;
  uint32_t* hm = hmir32 + (size_t)grp * 2 * SLOTW;

  #pragma unroll 1
  for (int t = 0; t < T_; ++t) {
    short8 axf = *(const short8*)(xrow + t * F_);

    // kc=0 (x-only) MFMA — h-independent, overlaps first h-load flight
    float4_ acc[4];
    #pragma unroll
    for (int g = 0; g < 4; ++g) {
      float4_ z = (float4_){0.f, 0.f, 0.f, 0.f};
      acc[g] = __builtin_amdgcn_mfma_f32_16x16x32_bf16(axf, wreg[g][0], z, 0, 0, 0);
    }

    // tag-verified h A-frag load from slot (t+1)&1.
    // Lane L's data for blk=i*2+k2 is 16 CONTIGUOUS bytes at blk*1024+L*16:
    // cols i*32+quad*8+k2*4 .. +3, row l15, as (bf16<<16 | tag) words.
    const uint32_t tag = (uint32_t)t & 0xFFFFu;
    const u64t* hq64  = (const u64t*)(hb + ((size_t)((t + 1) & 1)) * SLOTW)
                      + (size_t)lane * 2;
    const u64t* hq64m = (const u64t*)(hm + ((size_t)((t + 1) & 1)) * SLOTW)
                      + (size_t)lane * 2;
    u64t q[44];
    bool okall;
    int tries = 0;
    do {
      #pragma unroll
      for (int i = 0; i < 11; ++i) {
        const u64t* pa = hq64 + (size_t)(2 * i) * 128;
        const u64t* pb = hq64 + (size_t)(2 * i + 1) * 128;
        q[4 * i + 0] = __hip_atomic_load(pa,     __ATOMIC_RELAXED, __HIP_MEMORY_SCOPE_AGENT);
        q[4 * i + 1] = __hip_atomic_load(pa + 1, __ATOMIC_RELAXED, __HIP_MEMORY_SCOPE_AGENT);
        q[4 * i + 2] = __hip_atomic_load(pb,     __ATOMIC_RELAXED, __HIP_MEMORY_SCOPE_AGENT);
        q[4 * i + 3] = __hip_atomic_load(pb + 1, __ATOMIC_RELAXED, __HIP_MEMORY_SCOPE_AGENT);
      }
      uint32_t bad = 0;
      #pragma unroll
      for (int i = 0; i < 44; ++i) {
        bad |= ((uint32_t)q[i] ^ tag);
        bad |= ((uint32_t)(q[i] >> 32) ^ tag);
      }
      okall = (bool)__all((int)((bad & 0xFFFFu) == 0));
      if (!okall && ++tries >= 48) hq64 = hq64m;  // uniform switch, no deadlock
    } while (!okall);

    // repack hi16 pairs -> bf16 A-frags; MFMA over kc=1..11
    // q[4i+k]: k=0 -> cols 0,1 of the lane's 8-col span; k=1 -> 2,3; etc.
    #pragma unroll
    for (int i = 0; i < 11; ++i) {
      union { uint32_t w[4]; short8 s; } u;
      #pragma unroll
      for (int k = 0; k < 4; ++k) {
        uint32_t lo = (uint32_t)q[4 * i + k];
        uint32_t hi = (uint32_t)(q[4 * i + k] >> 32);
        u.w[k] = (lo >> 16) | (hi & 0xFFFF0000u);
      }
      #pragma unroll
      for (int g = 0; g < 4; ++g)
        acc[g] = __builtin_amdgcn_mfma_f32_16x16x32_bf16(u.s, wreg[g][i + 1], acc[g], 0, 0, 0);
    }

    // update: lane covers rows quad*4+r at its col; gates in registers
    uint32_t* hwr  = hb + ((size_t)(t & 1)) * SLOTW;
    uint32_t* hwrm = hm + ((size_t)(t & 1)) * SLOTW;
    const uint32_t otag = (uint32_t)(t + 1) & 0xFFFFu;
    float hn[4];
    uint32_t wout[4];
    #pragma unroll
    for (int r = 0; r < 4; ++r) {
      float ig = __builtin_amdgcn_rcpf(1.f + __expf(-acc[0][r]));
      float fg = __builtin_amdgcn_rcpf(1.f + __expf(-acc[1][r]));
      float gg = fmaxf(acc[2][r], 0.f);
      float og = __builtin_amdgcn_rcpf(1.f + __expf(-acc[3][r]));
      float cn = fg * cst[r] + ig * gg;
      cst[r] = cn;
      hn[r] = og * fmaxf(cn, 0.f);
      short hs = f2bf(hn[r]);
      if (col == 350) hs = (short)0x3F80;        // bias-row input stays 1.0
      else if (col == 351) hs = 0;
      wout[r] = ((uint32_t)(unsigned short)hs << 16) | otag;
      // FAST: plain writeback store — stays dirty in the group's XCD L2
      __hip_atomic_store(hwr + fastoff + r * 4, wout[r],
                         __ATOMIC_RELAXED, __HIP_MEMORY_SCOPE_WORKGROUP);
    }
    // MIRROR: agent write-through (fire-and-forget, off critical path)
    #pragma unroll
    for (int r = 0; r < 4; ++r)
      __hip_atomic_store(hwrm + fastoff + r * 4, wout[r],
                         __ATOMIC_RELAXED, __HIP_MEMORY_SCOPE_AGENT);

    // dense head (off the critical path), into LDS
    #pragma unroll
    for (int r = 0; r < 4; ++r) {
      float s = hn[r] * dwv;
      s += __shfl_xor(s, 1); s += __shfl_xor(s, 2);
      s += __shfl_xor(s, 4); s += __shfl_xor(s, 8);
      if (l15 == 0) lds_part[wv][t][quad * 4 + r] = s;
    }
  }

  // bulk-store dense partials (once)
  __syncthreads();
  float* wp = wpart + ((size_t)(grp * NCB + j) * NB) * T_;
  for (int i = tid; i < NB * T_; i += 128) {
    int t = i & (T_ - 1), row = i >> 9;
    wp[(size_t)row * T_ + t] = lds_part[0][t][row] + lds_part[1][t][row];
  }
}

// ---- final: out[b,t] = db + sum_j wpart[grp][j][row][t] ----
__global__ void reduce_out(const float* __restrict__ wpart,
                           const float* __restrict__ dense_b,
                           float* __restrict__ out) {
  int i = blockIdx.x * 256 + threadIdx.x;   // i = b*T + t
  int b = i >> 9, t = i & 511;
  int grp = b >> 4, row = b & 15;
  float s = dense_b[0];
  #pragma unroll
  for (int j = 0; j < NCB; ++j)
    s += wpart[(((size_t)grp * NCB + j) * NB + row) * T_ + t];
  out[i] = s;
}

extern "C" void kernel_launch(void* const* d_in, const int* in_sizes, int n_in,
                              void* d_out, int out_size, void* d_ws, size_t ws_size,
                              hipStream_t stream) {
  const float* x    = (const float*)d_in[0];
  const float* kern = (const float*)d_in[1];
  const float* rk   = (const float*)d_in[2];
  const float* bias = (const float*)d_in[3];
  const float* dw   = (const float*)d_in[4];
  const float* db   = (const float*)d_in[5];
  float* out = (float*)d_out;

  char* ws = (char*)d_ws;
  short*    wswz   = (short*)(ws);
  short*    xbf    = (short*)(ws + OFF_XBF);
  uint32_t* hbuf32 = (uint32_t*)(ws + OFF_HBUF);
  uint32_t* hmir32 = (uint32_t*)(ws + OFF_HMIR);
  float*    wpart  = (float*)(ws + OFF_WP);

  prep_w<<<NT, 64, 0, stream>>>(kern, rk, bias, wswz);
  prep_x<<<(256 * T_ * F_) / (256 * 4), 256, 0, stream>>>(x, xbf);
  init_all<<<(NGRP * SLOTW) / 256, 256, 0, stream>>>(hbuf32, hmir32);
  lstm_kernel<<<NGRP * NCB, 128, 0, stream>>>(xbf, wswz, hbuf32, hmir32, dw, wpart);
  reduce_out<<<(256 * T_) / 256, 256, 0, stream>>>(wpart, db, out);
}

// Round 4
// 1000.452 us; speedup vs baseline: 2.7434x; 1.3366x over previous
//
#include <hip/hip_runtime.h>
#include <stdint.h>

// LSTM B=256,T=512,F=32,U=350; gates i,f,g(relu),o; h=o*relu(c); out=h.dw+db
//
// R11: split tags from data; bf16 data slab; no steady-state mirror stores.
//  R10 accounting (6k cy/step): VALU 940 (==1 attempt -> spin not looping),
//  MFMA 270, rest = stalls: (a) mirror agent-store HBM-ack drain at the
//  spin's vmcnt(0) (in-order retire; WRITE=367MB proves both buffers stream
//  to HBM), (b) 22.5KB tag-in-word slab re-loaded per wave per step (352
//  line-req x 44 waves/XCD ~ 1k cy L2 service) + 360cy tag-check VALU.
//  Changes:
//   - FAST data: pure bf16, A-frag order. slot = [11 blk][64 lane][16B]
//     (11264B). Consumer: 22 u64 agent loads -> short8 frags DIRECTLY
//     (no repack). Producer: 4 ushort stores (rows quad*4+r, stride 16B).
//   - TAGS: 22 u32 words/group/slot (word idx = tile). Producer publishes
//     with RELEASE-workgroup store (compiler emits vmcnt drain of the 4
//     L2-bound data stores, ~200cy). Spin = ONE 2-line tag load + ~15 VALU.
//     Data loads issue only after tags pass (same-L2 serialization makes
//     tag-then-data ordered; loads are atomics so not compiler-hoisted).
//   - MIRROR: steady-state ZERO stores. Distress protocol: if fast spin
//     stalls 16384 tries, raise system-scope flag; on flag, every wave
//     dumps wout (tag t) + wout_prev (tag t-1) to mirror in R10's
//     self-validating tag-in-word layout and thereafter produces+consumes
//     via the R10 mirror path. Step-spread <=1 (ping-pong proof) => the
//     2-deep dump covers all needed tags => no deadlock. Correctness never
//     depends on blockIdx->XCD mapping; flag polls are system-scope
//     (L2-bypass) every 64th try only.
//  Depth-2 ping-pong proof carries over verbatim (readers of slot s at
//  step t all finished before any tag-(t+2) publisher overwrites s).

#define T_   512
#define F_   32
#define U_   350
#define G4   1400
#define NGRP 16
#define NB   16
#define NCB  11
#define KC   12
#define NT   88
#define HSLOTUS 5632    // ushorts per bf16 fast slot (11 blk * 512)
#define SLOTW   5632    // u32 words per mirror slot (R10 layout)

typedef __attribute__((ext_vector_type(8))) short  short8;
typedef __attribute__((ext_vector_type(4))) short  short4_;
typedef __attribute__((ext_vector_type(4))) float  float4_;
typedef unsigned long long u64t;

__device__ __forceinline__ short f2bf(float f) {
  union { float f; uint32_t u; } v; v.f = f;
  return (short)((v.u + 0x7FFFu + ((v.u >> 16) & 1u)) >> 16);
}

// ---- workspace layout (bytes) ----
#define SZ_W     (NT*KC*64*8*2u)                        // 1,081,344
#define OFF_XBF  (SZ_W)
#define SZ_XBF   (256u*T_*F_*2u)                        // 8,388,608
#define OFF_HBUF (OFF_XBF + SZ_XBF)
#define SZ_HBUF  (NGRP*2u*HSLOTUS*2u)                   // 360,448
#define OFF_HMIR (OFF_HBUF + SZ_HBUF)
#define SZ_HMIR  (NGRP*2u*SLOTW*4u)                     // 720,896
#define OFF_TAG  (OFF_HMIR + SZ_HMIR)
#define SZ_TAG   (NGRP*2u*32u*4u)                       // 4,096
#define OFF_FLG  (OFF_TAG + SZ_TAG)
#define SZ_FLG   (NGRP*16u*4u)                          // 1,024
#define OFF_WP   (OFF_FLG + SZ_FLG)
#define SZ_WP    (NGRP*NCB*NB*T_*4u)                    // 5,767,168

// ---- prep: W_swz[kc][tile][lane][8] bf16 in MFMA B-fragment order ----
__global__ void prep_w(const float* __restrict__ kern,
                       const float* __restrict__ rk,
                       const float* __restrict__ bias,
                       short* __restrict__ wswz) {
  const int tile = blockIdx.x, lane = threadIdx.x;
  const int g = tile / 22, jt = tile % 22;
  const int colg = jt * 16 + (lane & 15);
  const int src = g * U_ + colg;
  const bool valid = (colg < U_);
  const int kbase = (lane >> 4) * 8;
  for (int kc = 0; kc < KC; ++kc) {
    short8 pack;
    #pragma unroll
    for (int jj = 0; jj < 8; ++jj) {
      int k = kc * 32 + kbase + jj;
      float v = 0.f;
      if (valid) {
        if (k < F_)            v = kern[k * G4 + src];
        else if (k < F_ + U_)  v = rk[(k - F_) * G4 + src];
        else if (k == F_ + U_) v = bias[src];
      }
      pack[jj] = f2bf(v);
    }
    *(short8*)(wswz + (((size_t)kc * NT + tile) * 64 + lane) * 8) = pack;
  }
}

// ---- prep: x f32 -> bf16 ([b][t][f], contiguous 16B A-frag loads) ----
__global__ void prep_x(const float* __restrict__ x, short* __restrict__ xbf) {
  int i = (blockIdx.x * 256 + threadIdx.x) * 4;
  float4_ v = *(const float4_*)(x + i);
  short4_ o;
  #pragma unroll
  for (int jj = 0; jj < 4; ++jj) o[jj] = f2bf(v[jj]);
  *(short4_*)(xbf + i) = o;
}

// ---- init: slot1 = h_{-1}=0 tag 0 (bias col 350 = 1.0); tags; flag ----
// Fast slot0 / mirror slot0 need no init (reads are tag-gated / tag-in-word
// poison-safe). Tag slot0 init 0 is safe: slot0 wants odd tags only.
__global__ void init_all(unsigned short* __restrict__ hb16,
                         uint32_t* __restrict__ hmir32,
                         uint32_t* __restrict__ tagbuf,
                         uint32_t* __restrict__ flagbuf) {
  int i = blockIdx.x * 256 + threadIdx.x;            // 0 .. NGRP*5632-1
  int grp = i / HSLOTUS, rem = i % HSLOTUS;
  // fast bf16 slot1: rem = blk*512 + (quad_c*16+row)*8 + cpos
  {
    int blk = rem >> 9, quadc = (rem >> 7) & 3, cpos = rem & 7;
    int col = blk * 32 + quadc * 8 + cpos;
    hb16[(size_t)(grp * 2 + 1) * HSLOTUS + rem] =
        (col == 350) ? (unsigned short)0x3F80 : 0;
  }
  // mirror slot1 (R10 tag-in-word layout)
  {
    int blkm = rem >> 8, off = rem & 255;
    int fi = blkm >> 1, fk2 = blkm & 1, fquadc = off >> 6;
    int fk1 = (off >> 1) & 1, fb = off & 1;
    int fcol = fi * 32 + fquadc * 8 + fk2 * 4 + fk1 * 2 + fb;
    hmir32[(size_t)(grp * 2 + 1) * SLOTW + rem] =
        (fcol == 350) ? 0x3F800000u : 0u;
  }
  if (rem < 32) {
    tagbuf[(size_t)(grp * 2 + 0) * 32 + rem] = 0u;
    tagbuf[(size_t)(grp * 2 + 1) * 32 + rem] = 0u;
  }
  if (rem == 0) flagbuf[grp * 16] = 0u;
}

// ---- main: persistent, 2 decoupled waves per block, weights in regs ----
__global__ __launch_bounds__(128)
__attribute__((amdgpu_waves_per_eu(1, 1)))
void lstm_kernel(const short* __restrict__ xbf, const short* __restrict__ wswz,
                 unsigned short* __restrict__ hb16, uint32_t* __restrict__ hmir32,
                 uint32_t* __restrict__ tagbuf, uint32_t* __restrict__ flagbuf,
                 const float* __restrict__ dense_w, float* __restrict__ wpart) {
  __shared__ float lds_part[2][T_][16];   // 64 KB dense-head partials

  const int tid  = threadIdx.x;
  const int lane = tid & 63;
  const int wv   = tid >> 6;            // 0..1
  const int l15  = lane & 15;
  const int quad = lane >> 4;
  const int grp  = blockIdx.x & 15;     // same-XCD heuristic (fast path only)
  const int j    = blockIdx.x >> 4;     // 0..10
  const int tileg = 2 * j + wv;         // this wave's col tile 0..21

  // weights -> registers ONCE
  short8 wreg[4][KC];
  #pragma unroll
  for (int g = 0; g < 4; ++g)
    #pragma unroll
    for (int kc = 0; kc < KC; ++kc)
      wreg[g][kc] = *(const short8*)(wswz +
          (((size_t)kc * NT + (g * 22 + tileg)) * 64 + lane) * 8);

  const int col = tileg * 16 + l15;               // gate-relative col 0..351
  const float dwv = (col < U_) ? dense_w[col] : 0.f;
  float cst[4] = {0.f, 0.f, 0.f, 0.f};

  // fast bf16 producer: ushort idx = pbase_us + r*8 (rows quad*4+r)
  const int pblk = col >> 5, pc32 = col & 31;
  const int pbase_us = pblk * 512 + ((pc32 >> 3) * 16 + quad * 4) * 8 + (pc32 & 7);
  // mirror (R10 tag-in-word) offset, +r*4 per row
  const int colrem = col & 31;
  const int fastoff = (((col >> 5) * 2 + ((colrem >> 2) & 1)) * 256)
                    + (((colrem >> 3) * 16 + quad * 4) * 4)
                    + (((colrem >> 1) & 1) * 2) + (col & 1);

  const short* xrow = xbf + ((size_t)(grp * NB + l15) * T_) * F_ + quad * 8;
  unsigned short* hbb = hb16 + (size_t)grp * 2 * HSLOTUS;
  uint32_t* hm  = hmir32 + (size_t)grp * 2 * SLOTW;
  uint32_t* tgg = tagbuf + (size_t)grp * 2 * 32;
  uint32_t* flagp = flagbuf + grp * 16;
  const int tagidx = (lane < 22) ? lane : 31;     // word31: always 0

  bool mm = false;                                 // mirror (degraded) mode
  const short hs_init = (col == 350) ? (short)0x3F80 : 0;
  uint32_t wout[4], wout_prev[4];
  #pragma unroll
  for (int r = 0; r < 4; ++r)
    wout[r] = wout_prev[r] = ((uint32_t)(unsigned short)hs_init) << 16;

  #pragma unroll 1
  for (int t = 0; t < T_; ++t) {
    short8 axf = *(const short8*)(xrow + t * F_);

    // first tag probe issued BEFORE kc=0 MFMAs (latency overlap)
    const uint32_t want = (uint32_t)t;
    const uint32_t* tgr = tgg + (size_t)((t + 1) & 1) * 32;
    uint32_t tv = __hip_atomic_load(tgr + tagidx, __ATOMIC_RELAXED,
                                    __HIP_MEMORY_SCOPE_AGENT);

    // kc=0 (x-only) MFMA — h-independent
    float4_ acc[4];
    #pragma unroll
    for (int g = 0; g < 4; ++g) {
      float4_ z = (float4_){0.f, 0.f, 0.f, 0.f};
      acc[g] = __builtin_amdgcn_mfma_f32_16x16x32_bf16(axf, wreg[g][0], z, 0, 0, 0);
    }

    short8 afr[11];
    bool ready = (bool)__all((int)(lane >= 22 || tv == want));
    bool gotm = false;
    int tries = 0;
    while (!ready) {
      ++tries;
      if (!mm) {
        if ((tries & 63) == 0) {                    // poll distress (system)
          uint32_t f = __hip_atomic_load(flagp, __ATOMIC_RELAXED,
                                         __HIP_MEMORY_SCOPE_SYSTEM);
          if (f) mm = true;
        }
        if (tries == 16384) {                       // raise distress
          if (lane == 0)
            __hip_atomic_store(flagp, 1u, __ATOMIC_RELAXED,
                               __HIP_MEMORY_SCOPE_SYSTEM);
          mm = true;
        }
        if (mm) {
          // dump last two h vectors (self-validating tag-in-word)
          uint32_t* md1 = hm + (size_t)((t + 1) & 1) * SLOTW + fastoff; // tag t
          uint32_t* md0 = hm + (size_t)(t & 1) * SLOTW + fastoff;      // tag t-1
          #pragma unroll
          for (int r = 0; r < 4; ++r) {
            __hip_atomic_store(md1 + r * 4, wout[r], __ATOMIC_RELAXED,
                               __HIP_MEMORY_SCOPE_AGENT);
            __hip_atomic_store(md0 + r * 4, wout_prev[r], __ATOMIC_RELAXED,
                               __HIP_MEMORY_SCOPE_AGENT);
          }
        }
      } else {
        // mirror attempt: R10's coalesced tag-in-word path
        const u64t* mq = (const u64t*)(hm + (size_t)((t + 1) & 1) * SLOTW)
                       + (size_t)lane * 2;
        u64t q[44];
        #pragma unroll
        for (int i = 0; i < 11; ++i) {
          const u64t* pa = mq + (size_t)(2 * i) * 128;
          const u64t* pb = mq + (size_t)(2 * i + 1) * 128;
          q[4 * i + 0] = __hip_atomic_load(pa,     __ATOMIC_RELAXED, __HIP_MEMORY_SCOPE_AGENT);
          q[4 * i + 1] = __hip_atomic_load(pa + 1, __ATOMIC_RELAXED, __HIP_MEMORY_SCOPE_AGENT);
          q[4 * i + 2] = __hip_atomic_load(pb,     __ATOMIC_RELAXED, __HIP_MEMORY_SCOPE_AGENT);
          q[4 * i + 3] = __hip_atomic_load(pb + 1, __ATOMIC_RELAXED, __HIP_MEMORY_SCOPE_AGENT);
        }
        const uint32_t tag16 = want & 0xFFFFu;
        uint32_t bad = 0;
        #pragma unroll
        for (int i = 0; i < 44; ++i) {
          bad |= ((uint32_t)q[i] ^ tag16);
          bad |= ((uint32_t)(q[i] >> 32) ^ tag16);
        }
        if ((bool)__all((int)((bad & 0xFFFFu) == 0))) {
          #pragma unroll
          for (int i = 0; i < 11; ++i) {
            union { uint32_t w[4]; short8 s; } u;
            #pragma unroll
            for (int k = 0; k < 4; ++k) {
              uint32_t lo = (uint32_t)q[4 * i + k];
              uint32_t hi = (uint32_t)(q[4 * i + k] >> 32);
              u.w[k] = (lo >> 16) | (hi & 0xFFFF0000u);
            }
            afr[i] = u.s;
          }
          gotm = true;
          break;
        }
      }
      tv = __hip_atomic_load(tgr + tagidx, __ATOMIC_RELAXED,
                             __HIP_MEMORY_SCOPE_AGENT);
      ready = (bool)__all((int)(lane >= 22 || tv == want));
    }

    if (!gotm) {
      // coalesced bf16 A-frag load: lane L reads 16B at blk*1024 + L*16
      const u64t* hq = (const u64t*)(hbb + (size_t)((t + 1) & 1) * HSLOTUS)
                     + (size_t)lane * 2;
      #pragma unroll
      for (int i = 0; i < 11; ++i) {
        union { u64t q[2]; short8 s; } u;
        u.q[0] = __hip_atomic_load(hq + (size_t)i * 128,     __ATOMIC_RELAXED, __HIP_MEMORY_SCOPE_AGENT);
        u.q[1] = __hip_atomic_load(hq + (size_t)i * 128 + 1, __ATOMIC_RELAXED, __HIP_MEMORY_SCOPE_AGENT);
        afr[i] = u.s;
      }
    }

    // MFMA over kc=1..11 (no repack needed)
    #pragma unroll
    for (int i = 0; i < 11; ++i)
      #pragma unroll
      for (int g = 0; g < 4; ++g)
        acc[g] = __builtin_amdgcn_mfma_f32_16x16x32_bf16(afr[i], wreg[g][i + 1], acc[g], 0, 0, 0);

    // update: lane covers rows quad*4+r at its col; gates in registers
    unsigned short* hwp = hbb + (size_t)(t & 1) * HSLOTUS + pbase_us;
    const uint32_t otag = (uint32_t)(t + 1);
    float hn[4];
    #pragma unroll
    for (int r = 0; r < 4; ++r) {
      float ig = __builtin_amdgcn_rcpf(1.f + __expf(-acc[0][r]));
      float fg = __builtin_amdgcn_rcpf(1.f + __expf(-acc[1][r]));
      float gg = fmaxf(acc[2][r], 0.f);
      float og = __builtin_amdgcn_rcpf(1.f + __expf(-acc[3][r]));
      float cn = fg * cst[r] + ig * gg;
      cst[r] = cn;
      hn[r] = og * fmaxf(cn, 0.f);
      short hs = f2bf(hn[r]);
      if (col == 350) hs = (short)0x3F80;        // bias-row input stays 1.0
      else if (col == 351) hs = 0;
      wout_prev[r] = wout[r];
      wout[r] = (((uint32_t)(unsigned short)hs) << 16) | (otag & 0xFFFFu);
      hwp[r * 8] = (unsigned short)hs;           // fast bf16 data store (L2)
    }
    // publish tag with RELEASE (drains the 4 data stores first)
    if (lane == 0)
      __hip_atomic_store(tgg + (size_t)(t & 1) * 32 + tileg, otag,
                         __ATOMIC_RELEASE, __HIP_MEMORY_SCOPE_WORKGROUP);
    // degraded mode: also keep the coherent mirror current
    if (mm) {
      uint32_t* hwrm = hm + (size_t)(t & 1) * SLOTW + fastoff;
      #pragma unroll
      for (int r = 0; r < 4; ++r)
        __hip_atomic_store(hwrm + r * 4, wout[r], __ATOMIC_RELAXED,
                           __HIP_MEMORY_SCOPE_AGENT);
    }

    // dense head (off the critical path), into LDS
    #pragma unroll
    for (int r = 0; r < 4; ++r) {
      float s = hn[r] * dwv;
      s += __shfl_xor(s, 1); s += __shfl_xor(s, 2);
      s += __shfl_xor(s, 4); s += __shfl_xor(s, 8);
      if (l15 == 0) lds_part[wv][t][quad * 4 + r] = s;
    }
  }

  // bulk-store dense partials (once)
  __syncthreads();
  float* wp = wpart + ((size_t)(grp * NCB + j) * NB) * T_;
  for (int i = tid; i < NB * T_; i += 128) {
    int t = i & (T_ - 1), row = i >> 9;
    wp[(size_t)row * T_ + t] = lds_part[0][t][row] + lds_part[1][t][row];
  }
}

// ---- final: out[b,t] = db + sum_j wpart[grp][j][row][t] ----
__global__ void reduce_out(const float* __restrict__ wpart,
                           const float* __restrict__ dense_b,
                           float* __restrict__ out) {
  int i = blockIdx.x * 256 + threadIdx.x;   // i = b*T + t
  int b = i >> 9, t = i & 511;
  int grp = b >> 4, row = b & 15;
  float s = dense_b[0];
  #pragma unroll
  for (int j = 0; j < NCB; ++j)
    s += wpart[(((size_t)grp * NCB + j) * NB + row) * T_ + t];
  out[i] = s;
}

extern "C" void kernel_launch(void* const* d_in, const int* in_sizes, int n_in,
                              void* d_out, int out_size, void* d_ws, size_t ws_size,
                              hipStream_t stream) {
  const float* x    = (const float*)d_in[0];
  const float* kern = (const float*)d_in[1];
  const float* rk   = (const float*)d_in[2];
  const float* bias = (const float*)d_in[3];
  const float* dw   = (const float*)d_in[4];
  const float* db   = (const float*)d_in[5];
  float* out = (float*)d_out;

  char* ws = (char*)d_ws;
  short*          wswz   = (short*)(ws);
  short*          xbf    = (short*)(ws + OFF_XBF);
  unsigned short* hb16   = (unsigned short*)(ws + OFF_HBUF);
  uint32_t*       hmir32 = (uint32_t*)(ws + OFF_HMIR);
  uint32_t*       tagbuf = (uint32_t*)(ws + OFF_TAG);
  uint32_t*       flagbuf= (uint32_t*)(ws + OFF_FLG);
  float*          wpart  = (float*)(ws + OFF_WP);

  prep_w<<<NT, 64, 0, stream>>>(kern, rk, bias, wswz);
  prep_x<<<(256 * T_ * F_) / (256 * 4), 256, 0, stream>>>(x, xbf);
  init_all<<<(NGRP * HSLOTUS) / 256, 256, 0, stream>>>(hb16, hmir32, tagbuf, flagbuf);
  lstm_kernel<<<NGRP * NCB, 128, 0, stream>>>(xbf, wswz, hb16, hmir32, tagbuf,
                                              flagbuf, dw, wpart);
  reduce_out<<<(256 * T_) / 256, 256, 0, stream>>>(wpart, db, out);
}